// Round 16
// baseline (1148.268 us; speedup 1.0000x reference)
//
#include <hip/hip_runtime.h>
#include <hip/hip_bf16.h>

#define T_STEPS 100
#define NG 4096
#define NP 512

typedef __bf16 bf16x8 __attribute__((ext_vector_type(8)));
typedef float f32x4 __attribute__((ext_vector_type(4)));

__device__ __forceinline__ f32x4 mfma_bf16(bf16x8 a, bf16x8 b, f32x4 c) {
  return __builtin_amdgcn_mfma_f32_16x16x32_bf16(a, b, c, 0, 0, 0);
}

// async global->LDS, 16B per lane; LDS dest = wave-uniform base + lane*16
__device__ __forceinline__ void gload16(const void* g, void* l) {
  __builtin_amdgcn_global_load_lds(
      (const __attribute__((address_space(1))) void*)g,
      (__attribute__((address_space(3))) void*)l, 16, 0, 0);
}

__device__ __forceinline__ float bf2f(unsigned short u) {
  return __uint_as_float((unsigned)u << 16);
}

// ---------------- f32 -> bf16 conversion, 8 elems/thread ----------------
__global__ __launch_bounds__(256) void cvt_bf16_kernel(const float* __restrict__ in,
                                                       __hip_bfloat16* __restrict__ out,
                                                       int n8) {
  int i = blockIdx.x * 256 + threadIdx.x;
  if (i >= n8) return;
  const float4* p = reinterpret_cast<const float4*>(in) + (size_t)i * 2;
  float4 f0 = p[0], f1 = p[1];
  union { __hip_bfloat16 h[8]; uint4 u; } z;
  z.h[0] = __float2bfloat16(f0.x); z.h[1] = __float2bfloat16(f0.y);
  z.h[2] = __float2bfloat16(f0.z); z.h[3] = __float2bfloat16(f0.w);
  z.h[4] = __float2bfloat16(f1.x); z.h[5] = __float2bfloat16(f1.y);
  z.h[6] = __float2bfloat16(f1.z); z.h[7] = __float2bfloat16(f1.w);
  *(reinterpret_cast<uint4*>(out) + i) = z.u;
}

// ---------------- encoder: h0 = p0 @ W_enc^T  -> bf16 -------------------
__global__ __launch_bounds__(256) void encoder_kernel(const float* __restrict__ p0,
                                                      const float* __restrict__ Wenc,
                                                      __hip_bfloat16* __restrict__ h0) {
  __shared__ float sp[64 * 129];
  const int tid = threadIdx.x;
  const int nb = blockIdx.x * 16;
  const int b = tid & 63;
  const int jg = tid >> 6;
  float acc[4] = {0.f, 0.f, 0.f, 0.f};
  for (int kc = 0; kc < NP; kc += 128) {
    __syncthreads();
    #pragma unroll
    for (int i = 0; i < 32; ++i) {
      int e = tid + i * 256;
      int bb = e >> 7, kk = e & 127;
      sp[bb * 129 + kk] = p0[bb * NP + kc + kk];
    }
    __syncthreads();
    for (int kk = 0; kk < 128; ++kk) {
      float pv = sp[b * 129 + kk];
      #pragma unroll
      for (int jj = 0; jj < 4; ++jj)
        acc[jj] += pv * Wenc[(size_t)(nb + jg * 4 + jj) * NP + kc + kk];
    }
  }
  #pragma unroll
  for (int jj = 0; jj < 4; ++jj)
    h0[(size_t)b * NG + nb + jg * 4 + jj] = __float2bfloat16(acc[jj]);
}

// ---------------- RNN GEMM partial, 4-buffer ring + counted vmcnt -------
// grid (64 ng, 8 kq) -- ng FASTEST => XCD = ng%8: all 8 kq-partials of an
// n-tile are computed on ONE XCD (zpart slice L2-local for the epi); each
// XCD's B panel (8 n-tiles x full K = 4 MB) is L2-resident across steps.
// Block 256 = 4 waves (ms,ns 2x2), tile 64b x 64n x 512k, BK=64 -> 8 iters.
// 4-buffer ring (64 KB LDS, grid caps occupancy at 2 blocks/CU anyway):
// issue->consume distance 3 iters; waits vmcnt(8)/(4)/(0). Stage is issued
// AFTER the barrier (WAR-safe: buffer (it+3)%4 = (it-1)%4 was consumed
// before every wave passed iter-it's barrier).
// k ascending (it*64 + ks*32) => zpart bitwise identical to r15.
__global__ __launch_bounds__(256, 2) void rnn_gemm_kernel(
    const __hip_bfloat16* __restrict__ A, int strideA,
    const __hip_bfloat16* __restrict__ Wh,
    __hip_bfloat16* __restrict__ zpart) {
  __shared__ char smem[65536];   // [4 bufs][A 8KB | B 8KB]
  const int tid = threadIdx.x;
  const int lane = tid & 63;
  const int w = tid >> 6;
  const int ms = w >> 1, ns = w & 1;
  const int ng = blockIdx.x, kq = blockIdx.y;   // ng fastest -> XCD = ng%8
  const int r = lane & 15;
  const int kg = lane >> 4;
  const int n0 = ng * 64;

  const __hip_bfloat16* gA = A + (size_t)kq * 512;
  const __hip_bfloat16* gB = Wh + (size_t)n0 * NG + (size_t)kq * 512;

  const int xsw = (kg ^ (r & 3)) << 4;
  const int x6 = (r & 4) << 4;
  const int ksX[2] = {0 ^ x6, 64 ^ x6};
  const int xA0 = (ms * 32 + r) * 128 + xsw;
  const int xA1 = xA0 + 16 * 128;
  const int xB0 = 8192 + (ns * 32 + r) * 128 + xsw;
  const int xB1 = xB0 + 16 * 128;

  auto stageA = [&](int buf, int it) {
    #pragma unroll
    for (int i = 0; i < 2; ++i) {
      int c = i * 256 + tid;
      int row = c >> 3;               // 8 chunks per 128B row
      int colB = (c & 7) * 16;
      int srcB = colB ^ ((row & 7) << 4);
      const char* src = (const char*)(gA + (size_t)row * strideA + it * 64) + srcB;
      gload16(src, smem + buf * 16384 + i * 4096 + w * 1024);
    }
  };
  auto stageB = [&](int buf, int it) {
    #pragma unroll
    for (int i = 0; i < 2; ++i) {
      int c = i * 256 + tid;
      int row = c >> 3;
      int colB = (c & 7) * 16;
      int srcB = colB ^ ((row & 7) << 4);
      const char* src = (const char*)(gB + (size_t)row * NG + it * 64) + srcB;
      gload16(src, smem + buf * 16384 + 8192 + i * 4096 + w * 1024);
    }
  };

  stageA(0, 0); stageB(0, 0);       // 4 ops
  stageA(1, 1); stageB(1, 1);       // 8 ops
  stageA(2, 2); stageB(2, 2);       // 12 ops outstanding

  f32x4 acc00{}, acc01{}, acc10{}, acc11{};
  #pragma unroll
  for (int it = 0; it < 8; ++it) {
    if (it == 7)      asm volatile("s_waitcnt vmcnt(0)" ::: "memory");
    else if (it == 6) asm volatile("s_waitcnt vmcnt(4)" ::: "memory");
    else              asm volatile("s_waitcnt vmcnt(8)" ::: "memory");
    __builtin_amdgcn_s_barrier();
    __builtin_amdgcn_sched_barrier(0);
    if (it < 5) { stageA((it + 3) & 3, it + 3); stageB((it + 3) & 3, it + 3); }
    const char* bb = smem + (it & 3) * 16384;
    #pragma unroll
    for (int ks = 0; ks < 2; ++ks) {          // k = it*64 + ks*32 ascending
      bf16x8 a0 = *(const bf16x8*)(bb + xA0 + ksX[ks]);
      bf16x8 a1 = *(const bf16x8*)(bb + xA1 + ksX[ks]);
      bf16x8 b0 = *(const bf16x8*)(bb + xB0 + ksX[ks]);
      bf16x8 b1 = *(const bf16x8*)(bb + xB1 + ksX[ks]);
      acc00 = mfma_bf16(a0, b0, acc00);
      acc01 = mfma_bf16(a0, b1, acc01);
      acc10 = mfma_bf16(a1, b0, acc10);
      acc11 = mfma_bf16(a1, b1, acc11);
    }
  }

  __hip_bfloat16* zb = zpart + ((size_t)(kq * 64 + ms * 32 + kg * 4) << 12)
                     + n0 + ns * 32 + r;
  #pragma unroll
  for (int j = 0; j < 4; ++j) {
    zb[(size_t)j * NG]             = __float2bfloat16(acc00[j]);
    zb[(size_t)j * NG + 16]        = __float2bfloat16(acc01[j]);
    zb[(size_t)(16 + j) * NG]      = __float2bfloat16(acc10[j]);
    zb[(size_t)(16 + j) * NG + 16] = __float2bfloat16(acc11[j]);
  }
}

// ---------------- RNN epilogue: truly XCD-local, bf16 state -------------
// grid (8 xg, 32 sub): XCD = linear%8 = xg. Block xg handles the n-tiles
// with ng%8 == xg (scattered j = 0..7: n = (xg+8j)*64 + c) -- exactly the
// slices whose zpart was WRITTEN on XCD xg (ng-fastest gemm grid). All
// zpart/vv/zp/gs accesses are XCD-local; vv/zp slice ownership is stable
// across steps. Fixed kq order => bitwise identical sum.
__global__ __launch_bounds__(256) void rnn_epi_kernel(
    const __hip_bfloat16* __restrict__ zpart,
    const float* __restrict__ v, const float* __restrict__ Win,
    unsigned short* __restrict__ vv, unsigned short* __restrict__ zp,
    __hip_bfloat16* __restrict__ gs, int t) {
  const int xg = blockIdx.x;
  const int sub = blockIdx.y;
  const int tid = threadIdx.x;
  const int b = sub * 2 + (tid >> 7);
  const int idx128 = (tid & 127) * 4;          // 0..508
  const int j = idx128 >> 6;                   // which of 8 scattered tiles
  const int c = idx128 & 63;                   // offset within 64-tile
  const int n = (xg + 8 * j) * 64 + c;

  f32x4 s{};
  const unsigned short* zu = (const unsigned short*)zpart;
  #pragma unroll
  for (int kq = 0; kq < 8; ++kq) {             // fixed order: deterministic
    ushort4 u = *(const ushort4*)(zu + ((size_t)(kq * 64 + b) << 12) + n);
    s[0] += bf2f(u.x); s[1] += bf2f(u.y); s[2] += bf2f(u.z); s[3] += bf2f(u.w);
  }
  float2 vt = *(const float2*)(v + (b * T_STEPS + t) * 2);
  float4 wA = *(const float4*)(Win + 2 * n);
  float4 wB = *(const float4*)(Win + 2 * n + 4);
  f32x4 z;
  z[0] = s[0] + vt.x * wA.x + vt.y * wA.y;
  z[1] = s[1] + vt.x * wA.z + vt.y * wA.w;
  z[2] = s[2] + vt.x * wB.x + vt.y * wB.y;
  z[3] = s[3] + vt.x * wB.z + vt.y * wB.w;

  const size_t idx = ((size_t)b << 12) + n;
  ushort4 vvu = *(const ushort4*)(vv + idx);
  ushort4 zpu = *(const ushort4*)(zp + idx);
  union { __hip_bfloat16 h[4]; uint2 u2; } og, ov, oz;
  #pragma unroll
  for (int jj = 0; jj < 4; ++jj) {
    float vvo = bf2f(jj == 0 ? vvu.x : jj == 1 ? vvu.y : jj == 2 ? vvu.z : vvu.w);
    float zpo = bf2f(jj == 0 ? zpu.x : jj == 1 ? zpu.y : jj == 2 ? zpu.z : zpu.w);
    z[jj] -= 0.5f * vvo;                       // z uses OLD vv
    float vvn = fmaxf(vvo + 0.1f * (zpo - vvo), 0.f);
    ov.h[jj] = __float2bfloat16(vvn);
    oz.h[jj] = __float2bfloat16(z[jj]);        // pre-relu z
    og.h[jj] = __float2bfloat16(fmaxf(z[jj], 0.f));
  }
  *(uint2*)(vv + idx) = ov.u2;
  *(uint2*)(zp + idx) = oz.u2;
  *(uint2*)(gs + (size_t)(b * T_STEPS + t) * NG + n) = og.u2;
}

// ---------------- decoder: logits = gs @ W_dec^T, LDS-staged (r12) ------
__global__ __launch_bounds__(256, 4) void decoder_kernel(
    const __hip_bfloat16* __restrict__ gs,
    const __hip_bfloat16* __restrict__ Wd,
    float* __restrict__ out) {
  __shared__ char smem[40960];    // [2 dbuf][A 4KB | B 16KB]
  const int tid = threadIdx.x;
  const int lane = tid & 63;
  const int w = tid >> 6;         // wave = ns (n sub-tile)
  const int bid = blockIdx.x;
  const int xcd = bid & 7;
  const int i6 = bid >> 3;        // 0..99
  const int mtile = xcd * 25 + (i6 % 25);
  const int ntile = i6 / 25;
  const int m0 = mtile * 32;
  const int n0 = ntile * 128;
  const int r = lane & 15;
  const int kg = lane >> 4;

  const __hip_bfloat16* gA = gs + (size_t)m0 * NG;
  const __hip_bfloat16* gB = Wd + (size_t)n0 * NG;

  const int xsw = (kg * 16) ^ ((r & 3) << 4);
  const int x6 = (r & 4) << 4;
  const int ksX[2] = {0 ^ x6, 64 ^ x6};
  const int xA0 = r * 128 + xsw;
  const int xA1 = xA0 + 16 * 128;
  const int xB0 = (w * 32 + r) * 128 + xsw;
  const int xB1 = xB0 + 16 * 128;

  auto stageA = [&](int buf, int it) {
    int row = tid >> 3;
    int colB = (tid & 7) * 16;
    int srcB = colB ^ ((row & 7) << 4);
    const char* src = (const char*)(gA + (size_t)row * NG + it * 64) + srcB;
    gload16(src, smem + buf * 20480 + w * 1024);
  };
  auto stageB = [&](int buf, int it) {
    #pragma unroll
    for (int i = 0; i < 4; ++i) {
      int c = i * 256 + tid;
      int row = c >> 3;
      int colB = (c & 7) * 16;
      int srcB = colB ^ ((row & 7) << 4);
      const char* src = (const char*)(gB + (size_t)row * NG + it * 64) + srcB;
      gload16(src, smem + buf * 20480 + 4096 + i * 4096 + w * 1024);
    }
  };

  stageA(0, 0);
  stageB(0, 0);
  asm volatile("s_waitcnt vmcnt(0)" ::: "memory");
  __syncthreads();

  f32x4 acc00{}, acc01{}, acc10{}, acc11{};
  #pragma unroll 2
  for (int it = 0; it < 64; ++it) {
    const int buf = it & 1;
    if (it < 63) { stageA(buf ^ 1, it + 1); stageB(buf ^ 1, it + 1); }
    const char* bA = smem + buf * 20480;
    const char* bB = bA + 4096;
    #pragma unroll
    for (int ks = 0; ks < 2; ++ks) {
      bf16x8 a0 = *(const bf16x8*)(bA + xA0 + ksX[ks]);
      bf16x8 a1 = *(const bf16x8*)(bA + xA1 + ksX[ks]);
      bf16x8 b0 = *(const bf16x8*)(bB + xB0 + ksX[ks]);
      bf16x8 b1 = *(const bf16x8*)(bB + xB1 + ksX[ks]);
      acc00 = mfma_bf16(a0, b0, acc00);
      acc01 = mfma_bf16(a0, b1, acc01);
      acc10 = mfma_bf16(a1, b0, acc10);
      acc11 = mfma_bf16(a1, b1, acc11);
    }
    asm volatile("s_waitcnt vmcnt(0)" ::: "memory");
    __syncthreads();
  }

  #pragma unroll
  for (int j = 0; j < 4; ++j) {
    float* po0 = out + (size_t)(m0 + kg * 4 + j) * NP + n0 + w * 32;
    float* po1 = out + (size_t)(m0 + 16 + kg * 4 + j) * NP + n0 + w * 32;
    po0[r]      = acc00[j];
    po0[r + 16] = acc01[j];
    po1[r]      = acc10[j];
    po1[r + 16] = acc11[j];
  }
}

// ---------------- log_softmax over rows of 512 (in place) ---------------
__global__ __launch_bounds__(256) void logsoftmax_kernel(float* __restrict__ out) {
  float* row = out + (size_t)blockIdx.x * NP;
  const int tid = threadIdx.x;
  const int lane = tid & 63, wid = tid >> 6;
  float x0 = row[tid], x1 = row[tid + 256];
  float m = fmaxf(x0, x1);
  #pragma unroll
  for (int off = 32; off >= 1; off >>= 1) m = fmaxf(m, __shfl_xor(m, off));
  __shared__ float sred[8];
  if (lane == 0) sred[wid] = m;
  __syncthreads();
  m = fmaxf(fmaxf(sred[0], sred[1]), fmaxf(sred[2], sred[3]));
  float e = __expf(x0 - m) + __expf(x1 - m);
  #pragma unroll
  for (int off = 32; off >= 1; off >>= 1) e += __shfl_xor(e, off);
  if (lane == 0) sred[4 + wid] = e;
  __syncthreads();
  float lse = m + __logf(sred[4] + sred[5] + sred[6] + sred[7]);
  row[tid] = x0 - lse;
  row[tid + 256] = x1 - lse;
}

extern "C" void kernel_launch(void* const* d_in, const int* in_sizes, int n_in,
                              void* d_out, int out_size, void* d_ws, size_t ws_size,
                              hipStream_t stream) {
  const float* v    = (const float*)d_in[0];  // [64,100,2]
  const float* p0   = (const float*)d_in[1];  // [64,512]
  const float* Wenc = (const float*)d_in[2];  // [4096,512]
  const float* Win  = (const float*)d_in[3];  // [4096,2]
  const float* Wh   = (const float*)d_in[4];  // [4096,4096]
  const float* Wdec = (const float*)d_in[5];  // [512,4096]
  float* out = (float*)d_out;                 // [64,100,512]

  char* ws = (char*)d_ws;
  __hip_bfloat16* gs      = (__hip_bfloat16*)(ws);               // 52,428,800
  __hip_bfloat16* Wh_bf   = (__hip_bfloat16*)(ws + 52428800);    // 33,554,432
  __hip_bfloat16* zpart   = (__hip_bfloat16*)(ws + 85983232);    //  4,194,304 (bf16)
  __hip_bfloat16* Wdec_bf = (__hip_bfloat16*)(ws + 85983232);    // aliases zpart (used after RNN)
  unsigned short* vv      = (unsigned short*)(ws + 90177536);    //    524,288 (bf16)
  unsigned short* zp      = (unsigned short*)(ws + 90701824);    //    524,288 (bf16)
  __hip_bfloat16* h0_bf   = (__hip_bfloat16*)(ws + 91226112);    //    524,288
  // total 91,750,400 B

  hipMemsetAsync(vv, 0, 1048576, stream);   // vv + zp (contiguous, bf16)
  cvt_bf16_kernel<<<8192, 256, 0, stream>>>(Wh, Wh_bf, 2097152);
  encoder_kernel<<<256, 256, 0, stream>>>(p0, Wenc, h0_bf);

  for (int t = 0; t < T_STEPS; ++t) {
    const __hip_bfloat16* A = (t == 0) ? h0_bf : (gs + (size_t)(t - 1) * NG);
    int sA = (t == 0) ? NG : T_STEPS * NG;
    rnn_gemm_kernel<<<dim3(64, 8), 256, 0, stream>>>(A, sA, Wh_bf, zpart);
    rnn_epi_kernel<<<dim3(8, 32), 256, 0, stream>>>(zpart, v, Win, vv, zp, gs, t);
  }

  cvt_bf16_kernel<<<1024, 256, 0, stream>>>(Wdec, Wdec_bf, 262144);  // after RNN (aliases zpart)
  decoder_kernel<<<800, 256, 0, stream>>>(gs, Wdec_bf, out);
  logsoftmax_kernel<<<6400, 256, 0, stream>>>(out);
}

// Round 17
// 1092.115 us; speedup vs baseline: 1.0514x; 1.0514x over previous
//
#include <hip/hip_runtime.h>
#include <hip/hip_bf16.h>

#define T_STEPS 100
#define NG 4096
#define NP 512

typedef __bf16 bf16x8 __attribute__((ext_vector_type(8)));
typedef float f32x4 __attribute__((ext_vector_type(4)));

__device__ __forceinline__ f32x4 mfma_bf16(bf16x8 a, bf16x8 b, f32x4 c) {
  return __builtin_amdgcn_mfma_f32_16x16x32_bf16(a, b, c, 0, 0, 0);
}

// async global->LDS, 16B per lane; LDS dest = wave-uniform base + lane*16
__device__ __forceinline__ void gload16(const void* g, void* l) {
  __builtin_amdgcn_global_load_lds(
      (const __attribute__((address_space(1))) void*)g,
      (__attribute__((address_space(3))) void*)l, 16, 0, 0);
}

__device__ __forceinline__ float bf2f(unsigned short u) {
  return __uint_as_float((unsigned)u << 16);
}

// ---------------- f32 -> bf16 conversion, 8 elems/thread ----------------
__global__ __launch_bounds__(256) void cvt_bf16_kernel(const float* __restrict__ in,
                                                       __hip_bfloat16* __restrict__ out,
                                                       int n8) {
  int i = blockIdx.x * 256 + threadIdx.x;
  if (i >= n8) return;
  const float4* p = reinterpret_cast<const float4*>(in) + (size_t)i * 2;
  float4 f0 = p[0], f1 = p[1];
  union { __hip_bfloat16 h[8]; uint4 u; } z;
  z.h[0] = __float2bfloat16(f0.x); z.h[1] = __float2bfloat16(f0.y);
  z.h[2] = __float2bfloat16(f0.z); z.h[3] = __float2bfloat16(f0.w);
  z.h[4] = __float2bfloat16(f1.x); z.h[5] = __float2bfloat16(f1.y);
  z.h[6] = __float2bfloat16(f1.z); z.h[7] = __float2bfloat16(f1.w);
  *(reinterpret_cast<uint4*>(out) + i) = z.u;
}

// ---------------- encoder: h0 = p0 @ W_enc^T  -> bf16 -------------------
__global__ __launch_bounds__(256) void encoder_kernel(const float* __restrict__ p0,
                                                      const float* __restrict__ Wenc,
                                                      __hip_bfloat16* __restrict__ h0) {
  __shared__ float sp[64 * 129];
  const int tid = threadIdx.x;
  const int nb = blockIdx.x * 16;
  const int b = tid & 63;
  const int jg = tid >> 6;
  float acc[4] = {0.f, 0.f, 0.f, 0.f};
  for (int kc = 0; kc < NP; kc += 128) {
    __syncthreads();
    #pragma unroll
    for (int i = 0; i < 32; ++i) {
      int e = tid + i * 256;
      int bb = e >> 7, kk = e & 127;
      sp[bb * 129 + kk] = p0[bb * NP + kc + kk];
    }
    __syncthreads();
    for (int kk = 0; kk < 128; ++kk) {
      float pv = sp[b * 129 + kk];
      #pragma unroll
      for (int jj = 0; jj < 4; ++jj)
        acc[jj] += pv * Wenc[(size_t)(nb + jg * 4 + jj) * NP + kc + kk];
    }
  }
  #pragma unroll
  for (int jj = 0; jj < 4; ++jj)
    h0[(size_t)b * NG + nb + jg * 4 + jj] = __float2bfloat16(acc[jj]);
}

// ---------------- RNN GEMM partial, 3-buffer ring + counted vmcnt -------
// (round-15 configuration: kq-fastest grid, 48 KB LDS, 3 blocks/CU.
//  kq fastest => XCD = kq: each XCD reads only its own 64 KB A-slice.)
__global__ __launch_bounds__(256, 3) void rnn_gemm_kernel(
    const __hip_bfloat16* __restrict__ A, int strideA,
    const __hip_bfloat16* __restrict__ Wh,
    __hip_bfloat16* __restrict__ zpart) {
  __shared__ char smem[49152];   // [3 bufs][A 8KB | B 8KB]
  const int tid = threadIdx.x;
  const int lane = tid & 63;
  const int w = tid >> 6;
  const int ms = w >> 1, ns = w & 1;
  const int kq = blockIdx.x, ng = blockIdx.y;
  const int r = lane & 15;
  const int kg = lane >> 4;
  const int n0 = ng * 64;

  const __hip_bfloat16* gA = A + (size_t)kq * 512;
  const __hip_bfloat16* gB = Wh + (size_t)n0 * NG + (size_t)kq * 512;

  const int xsw = (kg ^ (r & 3)) << 4;
  const int x6 = (r & 4) << 4;
  const int ksX[2] = {0 ^ x6, 64 ^ x6};
  const int xA0 = (ms * 32 + r) * 128 + xsw;
  const int xA1 = xA0 + 16 * 128;
  const int xB0 = 8192 + (ns * 32 + r) * 128 + xsw;
  const int xB1 = xB0 + 16 * 128;

  auto stageA = [&](int buf, int it) {
    #pragma unroll
    for (int i = 0; i < 2; ++i) {
      int c = i * 256 + tid;
      int row = c >> 3;               // 8 chunks per 128B row
      int colB = (c & 7) * 16;
      int srcB = colB ^ ((row & 7) << 4);
      const char* src = (const char*)(gA + (size_t)row * strideA + it * 64) + srcB;
      gload16(src, smem + buf * 16384 + i * 4096 + w * 1024);
    }
  };
  auto stageB = [&](int buf, int it) {
    #pragma unroll
    for (int i = 0; i < 2; ++i) {
      int c = i * 256 + tid;
      int row = c >> 3;
      int colB = (c & 7) * 16;
      int srcB = colB ^ ((row & 7) << 4);
      const char* src = (const char*)(gB + (size_t)row * NG + it * 64) + srcB;
      gload16(src, smem + buf * 16384 + 8192 + i * 4096 + w * 1024);
    }
  };

  stageA(0, 0); stageB(0, 0);       // 4 ops
  stageA(1, 1); stageB(1, 1);       // 8 ops outstanding

  f32x4 acc00{}, acc01{}, acc10{}, acc11{};
  #pragma unroll
  for (int it = 0; it < 8; ++it) {
    if (it == 7) asm volatile("s_waitcnt vmcnt(0)" ::: "memory");
    else         asm volatile("s_waitcnt vmcnt(4)" ::: "memory");
    __builtin_amdgcn_s_barrier();
    __builtin_amdgcn_sched_barrier(0);
    if (it < 6) { stageA((it + 2) % 3, it + 2); stageB((it + 2) % 3, it + 2); }
    const char* bb = smem + (it % 3) * 16384;
    #pragma unroll
    for (int ks = 0; ks < 2; ++ks) {          // k = it*64 + ks*32 ascending
      bf16x8 a0 = *(const bf16x8*)(bb + xA0 + ksX[ks]);
      bf16x8 a1 = *(const bf16x8*)(bb + xA1 + ksX[ks]);
      bf16x8 b0 = *(const bf16x8*)(bb + xB0 + ksX[ks]);
      bf16x8 b1 = *(const bf16x8*)(bb + xB1 + ksX[ks]);
      acc00 = mfma_bf16(a0, b0, acc00);
      acc01 = mfma_bf16(a0, b1, acc01);
      acc10 = mfma_bf16(a1, b0, acc10);
      acc11 = mfma_bf16(a1, b1, acc11);
    }
  }

  __hip_bfloat16* zb = zpart + ((size_t)(kq * 64 + ms * 32 + kg * 4) << 12)
                     + n0 + ns * 32 + r;
  #pragma unroll
  for (int j = 0; j < 4; ++j) {
    zb[(size_t)j * NG]             = __float2bfloat16(acc00[j]);
    zb[(size_t)j * NG + 16]        = __float2bfloat16(acc01[j]);
    zb[(size_t)(16 + j) * NG]      = __float2bfloat16(acc10[j]);
    zb[(size_t)(16 + j) * NG + 16] = __float2bfloat16(acc11[j]);
  }
}

// ---------------- RNN epilogue: XCD-aligned, bf16 state (r15) -----------
__global__ __launch_bounds__(256) void rnn_epi_kernel(
    const __hip_bfloat16* __restrict__ zpart,
    const float* __restrict__ v, const float* __restrict__ Win,
    unsigned short* __restrict__ vv, unsigned short* __restrict__ zp,
    __hip_bfloat16* __restrict__ gs, int t) {
  const int kqg = blockIdx.x;
  const int sub = blockIdx.y;
  const int tid = threadIdx.x;
  const int b = sub * 2 + (tid >> 7);
  const int n = kqg * 512 + (tid & 127) * 4;

  f32x4 s{};
  const unsigned short* zu = (const unsigned short*)zpart;
  #pragma unroll
  for (int kq = 0; kq < 8; ++kq) {                // fixed order: deterministic
    ushort4 u = *(const ushort4*)(zu + ((size_t)(kq * 64 + b) << 12) + n);
    s[0] += bf2f(u.x); s[1] += bf2f(u.y); s[2] += bf2f(u.z); s[3] += bf2f(u.w);
  }
  float2 vt = *(const float2*)(v + (b * T_STEPS + t) * 2);
  float4 wA = *(const float4*)(Win + 2 * n);
  float4 wB = *(const float4*)(Win + 2 * n + 4);
  f32x4 z;
  z[0] = s[0] + vt.x * wA.x + vt.y * wA.y;
  z[1] = s[1] + vt.x * wA.z + vt.y * wA.w;
  z[2] = s[2] + vt.x * wB.x + vt.y * wB.y;
  z[3] = s[3] + vt.x * wB.z + vt.y * wB.w;

  const size_t idx = ((size_t)b << 12) + n;
  ushort4 vvu = *(const ushort4*)(vv + idx);
  ushort4 zpu = *(const ushort4*)(zp + idx);
  union { __hip_bfloat16 h[4]; uint2 u2; } og, ov, oz;
  #pragma unroll
  for (int j = 0; j < 4; ++j) {
    float vvo = bf2f(j == 0 ? vvu.x : j == 1 ? vvu.y : j == 2 ? vvu.z : vvu.w);
    float zpo = bf2f(j == 0 ? zpu.x : j == 1 ? zpu.y : j == 2 ? zpu.z : zpu.w);
    z[j] -= 0.5f * vvo;                          // z uses OLD vv
    float vvn = fmaxf(vvo + 0.1f * (zpo - vvo), 0.f);
    ov.h[j] = __float2bfloat16(vvn);
    oz.h[j] = __float2bfloat16(z[j]);            // pre-relu z
    og.h[j] = __float2bfloat16(fmaxf(z[j], 0.f));
  }
  *(uint2*)(vv + idx) = ov.u2;
  *(uint2*)(zp + idx) = oz.u2;
  *(uint2*)(gs + (size_t)(b * T_STEPS + t) * NG + n) = og.u2;
}

// ---------------- decoder: logits = gs @ W_dec^T, LDS-staged (r12) ------
__global__ __launch_bounds__(256, 4) void decoder_kernel(
    const __hip_bfloat16* __restrict__ gs,
    const __hip_bfloat16* __restrict__ Wd,
    float* __restrict__ out) {
  __shared__ char smem[40960];    // [2 dbuf][A 4KB | B 16KB]
  const int tid = threadIdx.x;
  const int lane = tid & 63;
  const int w = tid >> 6;         // wave = ns (n sub-tile)
  const int bid = blockIdx.x;
  const int xcd = bid & 7;
  const int i6 = bid >> 3;        // 0..99
  const int mtile = xcd * 25 + (i6 % 25);
  const int ntile = i6 / 25;
  const int m0 = mtile * 32;
  const int n0 = ntile * 128;
  const int r = lane & 15;
  const int kg = lane >> 4;

  const __hip_bfloat16* gA = gs + (size_t)m0 * NG;
  const __hip_bfloat16* gB = Wd + (size_t)n0 * NG;

  const int xsw = (kg * 16) ^ ((r & 3) << 4);
  const int x6 = (r & 4) << 4;
  const int ksX[2] = {0 ^ x6, 64 ^ x6};
  const int xA0 = r * 128 + xsw;
  const int xA1 = xA0 + 16 * 128;
  const int xB0 = (w * 32 + r) * 128 + xsw;
  const int xB1 = xB0 + 16 * 128;

  auto stageA = [&](int buf, int it) {
    int row = tid >> 3;
    int colB = (tid & 7) * 16;
    int srcB = colB ^ ((row & 7) << 4);
    const char* src = (const char*)(gA + (size_t)row * NG + it * 64) + srcB;
    gload16(src, smem + buf * 20480 + w * 1024);
  };
  auto stageB = [&](int buf, int it) {
    #pragma unroll
    for (int i = 0; i < 4; ++i) {
      int c = i * 256 + tid;
      int row = c >> 3;
      int colB = (c & 7) * 16;
      int srcB = colB ^ ((row & 7) << 4);
      const char* src = (const char*)(gB + (size_t)row * NG + it * 64) + srcB;
      gload16(src, smem + buf * 20480 + 4096 + i * 4096 + w * 1024);
    }
  };

  stageA(0, 0);
  stageB(0, 0);
  asm volatile("s_waitcnt vmcnt(0)" ::: "memory");
  __syncthreads();

  f32x4 acc00{}, acc01{}, acc10{}, acc11{};
  #pragma unroll 2
  for (int it = 0; it < 64; ++it) {
    const int buf = it & 1;
    if (it < 63) { stageA(buf ^ 1, it + 1); stageB(buf ^ 1, it + 1); }
    const char* bA = smem + buf * 20480;
    const char* bB = bA + 4096;
    #pragma unroll
    for (int ks = 0; ks < 2; ++ks) {
      bf16x8 a0 = *(const bf16x8*)(bA + xA0 + ksX[ks]);
      bf16x8 a1 = *(const bf16x8*)(bA + xA1 + ksX[ks]);
      bf16x8 b0 = *(const bf16x8*)(bB + xB0 + ksX[ks]);
      bf16x8 b1 = *(const bf16x8*)(bB + xB1 + ksX[ks]);
      acc00 = mfma_bf16(a0, b0, acc00);
      acc01 = mfma_bf16(a0, b1, acc01);
      acc10 = mfma_bf16(a1, b0, acc10);
      acc11 = mfma_bf16(a1, b1, acc11);
    }
    asm volatile("s_waitcnt vmcnt(0)" ::: "memory");
    __syncthreads();
  }

  #pragma unroll
  for (int j = 0; j < 4; ++j) {
    float* po0 = out + (size_t)(m0 + kg * 4 + j) * NP + n0 + w * 32;
    float* po1 = out + (size_t)(m0 + 16 + kg * 4 + j) * NP + n0 + w * 32;
    po0[r]      = acc00[j];
    po0[r + 16] = acc01[j];
    po1[r]      = acc10[j];
    po1[r + 16] = acc11[j];
  }
}

// ---------------- log_softmax over rows of 512 (in place) ---------------
__global__ __launch_bounds__(256) void logsoftmax_kernel(float* __restrict__ out) {
  float* row = out + (size_t)blockIdx.x * NP;
  const int tid = threadIdx.x;
  const int lane = tid & 63, wid = tid >> 6;
  float x0 = row[tid], x1 = row[tid + 256];
  float m = fmaxf(x0, x1);
  #pragma unroll
  for (int off = 32; off >= 1; off >>= 1) m = fmaxf(m, __shfl_xor(m, off));
  __shared__ float sred[8];
  if (lane == 0) sred[wid] = m;
  __syncthreads();
  m = fmaxf(fmaxf(sred[0], sred[1]), fmaxf(sred[2], sred[3]));
  float e = __expf(x0 - m) + __expf(x1 - m);
  #pragma unroll
  for (int off = 32; off >= 1; off >>= 1) e += __shfl_xor(e, off);
  if (lane == 0) sred[4 + wid] = e;
  __syncthreads();
  float lse = m + __logf(sred[4] + sred[5] + sred[6] + sred[7]);
  row[tid] = x0 - lse;
  row[tid + 256] = x1 - lse;
}

extern "C" void kernel_launch(void* const* d_in, const int* in_sizes, int n_in,
                              void* d_out, int out_size, void* d_ws, size_t ws_size,
                              hipStream_t stream) {
  const float* v    = (const float*)d_in[0];  // [64,100,2]
  const float* p0   = (const float*)d_in[1];  // [64,512]
  const float* Wenc = (const float*)d_in[2];  // [4096,512]
  const float* Win  = (const float*)d_in[3];  // [4096,2]
  const float* Wh   = (const float*)d_in[4];  // [4096,4096]
  const float* Wdec = (const float*)d_in[5];  // [512,4096]
  float* out = (float*)d_out;                 // [64,100,512]

  char* ws = (char*)d_ws;
  __hip_bfloat16* gs      = (__hip_bfloat16*)(ws);               // 52,428,800
  __hip_bfloat16* Wh_bf   = (__hip_bfloat16*)(ws + 52428800);    // 33,554,432
  __hip_bfloat16* zpart   = (__hip_bfloat16*)(ws + 85983232);    //  4,194,304 (bf16)
  __hip_bfloat16* Wdec_bf = (__hip_bfloat16*)(ws + 85983232);    // aliases zpart (used after RNN)
  unsigned short* vv      = (unsigned short*)(ws + 90177536);    //    524,288 (bf16)
  unsigned short* zp      = (unsigned short*)(ws + 90701824);    //    524,288 (bf16)
  __hip_bfloat16* h0_bf   = (__hip_bfloat16*)(ws + 91226112);    //    524,288
  // total 91,750,400 B

  hipMemsetAsync(vv, 0, 1048576, stream);   // vv + zp (contiguous, bf16)
  cvt_bf16_kernel<<<8192, 256, 0, stream>>>(Wh, Wh_bf, 2097152);
  encoder_kernel<<<256, 256, 0, stream>>>(p0, Wenc, h0_bf);

  for (int t = 0; t < T_STEPS; ++t) {
    const __hip_bfloat16* A = (t == 0) ? h0_bf : (gs + (size_t)(t - 1) * NG);
    int sA = (t == 0) ? NG : T_STEPS * NG;
    rnn_gemm_kernel<<<dim3(8, 64), 256, 0, stream>>>(A, sA, Wh_bf, zpart);
    rnn_epi_kernel<<<dim3(8, 32), 256, 0, stream>>>(zpart, v, Win, vv, zp, gs, t);
  }

  cvt_bf16_kernel<<<1024, 256, 0, stream>>>(Wdec, Wdec_bf, 262144);  // after RNN (aliases zpart)
  decoder_kernel<<<800, 256, 0, stream>>>(gs, Wdec_bf, out);
  logsoftmax_kernel<<<6400, 256, 0, stream>>>(out);
}